// Round 1
// 1212.308 us; speedup vs baseline: 1.1220x; 1.1220x over previous
//
#include <hip/hip_runtime.h>
#include <cstdint>
#include <cstddef>

// SlotAttentionV2 forward, MI355X — restructured pipeline.
// Key algebra: fold Wk/Wv out of the N-dimension.
//   dots_ij = (q_i @ Wk) . xhat_j + q_i.bk          -> q' (8x64) + c (8) per batch
//   updates_i = (Wv (Sum_j attn_ij xhat_j))/S_i + bv -> accumulate Uraw (8x64) + S only
// So only xhat (LN'd input, bf16, 128 MB) is ever streamed over N.
// k_ln:    pure LN+pack stream (256 MB rd, 128 MB wr).
// k_attn:  B*N-parallel (2048 blocks): MFMA QK^T + in-frag softmax + Uraw/S accum.
// k_init / k_update: per-batch small math (prior/reparam/GRU/MLP/post/KL/q/q').

#define B_   256
#define N_   4096
#define EPS_   1e-8f
#define SCALE_ 0.125f
#define OUT_SLOTS_ (B_ * 8 * 64)   // 131072

typedef unsigned short u16;
typedef unsigned int   u32;
typedef short s16x8 __attribute__((ext_vector_type(8)));
typedef float f32x4 __attribute__((ext_vector_type(4)));

__device__ inline float bf2f(u16 u) {
  union { u32 i; float f; } c; c.i = ((u32)u) << 16; return c.f;
}
__device__ inline u16 f2bf(float f) {
  union { u32 i; float f; } c; c.f = f;
  return (u16)((c.i + 0x7fffu + ((c.i >> 16) & 1u)) >> 16);
}
__device__ inline void bf2x2(u32 u, float& lo, float& hi) {
  union { u32 i; float f; } a, b;
  a.i = u << 16; b.i = u & 0xffff0000u;
  lo = a.f; hi = b.f;
}
__device__ inline float wredsum(float v) {
  #pragma unroll
  for (int o = 32; o; o >>= 1) v += __shfl_xor(v, o, 64);
  return v;
}

// ---------------- k_ln: LN(inputs) -> xhat bf16 ----------------
__global__ __launch_bounds__(256) void k_ln(
    const float* __restrict__ x, const float* __restrict__ gg,
    const float* __restrict__ bb, u16* __restrict__ XH)
{
  const int tid = threadIdx.x;
  const int xc = tid & 3;          // quarter of the 64-dim row
  const int rloc = tid >> 2;       // 0..63 row within group
  float4 g4[4], b4[4];
  #pragma unroll
  for (int j = 0; j < 4; j++) {
    g4[j] = *(const float4*)(gg + xc * 16 + j * 4);
    b4[j] = *(const float4*)(bb + xc * 16 + j * 4);
  }
  for (size_t base = (size_t)blockIdx.x * 64; base < (size_t)B_ * N_;
       base += (size_t)gridDim.x * 64) {
    const size_t row = base + rloc;
    const float* xr = x + row * 64 + xc * 16;
    float4 xv[4];
    #pragma unroll
    for (int j = 0; j < 4; j++) xv[j] = ((const float4*)xr)[j];
    float s = 0.f;
    #pragma unroll
    for (int j = 0; j < 4; j++) s += xv[j].x + xv[j].y + xv[j].z + xv[j].w;
    s += __shfl_xor(s, 1, 64); s += __shfl_xor(s, 2, 64);
    const float m = s * (1.0f / 64.0f);
    float vs = 0.f;
    #pragma unroll
    for (int j = 0; j < 4; j++) {
      float a0 = xv[j].x - m, a1 = xv[j].y - m, a2 = xv[j].z - m, a3 = xv[j].w - m;
      vs += a0*a0 + a1*a1 + a2*a2 + a3*a3;
    }
    vs += __shfl_xor(vs, 1, 64); vs += __shfl_xor(vs, 2, 64);
    const float rs = rsqrtf(vs * (1.0f / 64.0f) + 1e-5f);
    u32 pk[8];
    #pragma unroll
    for (int j = 0; j < 4; j++) {
      float h0 = (xv[j].x - m) * rs * g4[j].x + b4[j].x;
      float h1 = (xv[j].y - m) * rs * g4[j].y + b4[j].y;
      float h2 = (xv[j].z - m) * rs * g4[j].z + b4[j].z;
      float h3 = (xv[j].w - m) * rs * g4[j].w + b4[j].w;
      pk[j*2+0] = (u32)f2bf(h0) | ((u32)f2bf(h1) << 16);
      pk[j*2+1] = (u32)f2bf(h2) | ((u32)f2bf(h3) << 16);
    }
    u32* dst = (u32*)(XH + row * 64 + xc * 16);
    ((uint4*)dst)[0] = make_uint4(pk[0], pk[1], pk[2], pk[3]);
    ((uint4*)dst)[1] = make_uint4(pk[4], pk[5], pk[6], pk[7]);
  }
}

// ---------------- k_init: P0 (prior, reparam) + q/q'/c + zero accumulators ----
__global__ __launch_bounds__(512) void k_init(
    const float* __restrict__ slots0, const float* __restrict__ prior_slots,
    const float* __restrict__ eps_noise,
    const float* __restrict__ sr_W1, const float* __restrict__ sr_b1,
    const float* __restrict__ sr_W2, const float* __restrict__ sr_b2,
    const float* __restrict__ pr_W1, const float* __restrict__ pr_b1,
    const float* __restrict__ pr_W2, const float* __restrict__ pr_b2,
    const float* __restrict__ Wq, const float* __restrict__ bq,
    const float* __restrict__ Wk, const float* __restrict__ bk,
    float* __restrict__ SLOTS, float* __restrict__ PRIOR, float* __restrict__ KLb,
    u16* __restrict__ QP, float* __restrict__ Cb,
    float* __restrict__ Ubuf, float* __restrict__ Sbuf)
{
  __shared__ float sl[512], hid[1024], post[1024];
  const int tid = threadIdx.x, b = blockIdx.x;
  const int s = tid >> 6, d = tid & 63;
  sl[tid] = slots0[(size_t)b * 512 + tid];
  // prior hidden = relu(prior_slots @ pr_W1.T + pr_b1)
  #pragma unroll
  for (int kk = 0; kk < 2; kk++) {
    int idx = tid + kk * 512; int s2 = idx >> 7, h = idx & 127;
    const float* xr = prior_slots + ((size_t)b * 8 + s2) * 64;
    const float* wr = pr_W1 + h * 64;
    float a = pr_b1[h];
    #pragma unroll
    for (int ec = 0; ec < 16; ec++) {
      float4 xe = ((const float4*)xr)[ec]; float4 w = ((const float4*)wr)[ec];
      a = fmaf(xe.x,w.x,a); a = fmaf(xe.y,w.y,a); a = fmaf(xe.z,w.z,a); a = fmaf(xe.w,w.w,a);
    }
    hid[idx] = fmaxf(a, 0.f);
  }
  __syncthreads();
  // prior = hid @ pr_W2.T + pr_b2 -> global
  #pragma unroll
  for (int kk = 0; kk < 2; kk++) {
    int idx = tid + kk * 512; int s2 = idx >> 7, o = idx & 127;
    const float* hh = hid + s2 * 128; const float* wr = pr_W2 + o * 128;
    float a = pr_b2[o];
    #pragma unroll
    for (int ec = 0; ec < 32; ec++) {
      float4 xe = ((const float4*)hh)[ec]; float4 w = ((const float4*)wr)[ec];
      a = fmaf(xe.x,w.x,a); a = fmaf(xe.y,w.y,a); a = fmaf(xe.z,w.z,a); a = fmaf(xe.w,w.w,a);
    }
    PRIOR[(size_t)b * 1024 + idx] = a;
  }
  __syncthreads();
  // sms hidden
  #pragma unroll
  for (int kk = 0; kk < 2; kk++) {
    int idx = tid + kk * 512; int s2 = idx >> 7, h = idx & 127;
    const float* xr = sl + s2 * 64; const float* wr = sr_W1 + h * 64;
    float a = sr_b1[h];
    #pragma unroll
    for (int ec = 0; ec < 16; ec++) {
      float4 xe = ((const float4*)xr)[ec]; float4 w = ((const float4*)wr)[ec];
      a = fmaf(xe.x,w.x,a); a = fmaf(xe.y,w.y,a); a = fmaf(xe.z,w.z,a); a = fmaf(xe.w,w.w,a);
    }
    hid[idx] = fmaxf(a, 0.f);
  }
  __syncthreads();
  // sms = hid @ sr_W2.T + sr_b2
  #pragma unroll
  for (int kk = 0; kk < 2; kk++) {
    int idx = tid + kk * 512; int s2 = idx >> 7, o = idx & 127;
    const float* hh = hid + s2 * 128; const float* wr = sr_W2 + o * 128;
    float a = sr_b2[o];
    #pragma unroll
    for (int ec = 0; ec < 32; ec++) {
      float4 xe = ((const float4*)hh)[ec]; float4 w = ((const float4*)wr)[ec];
      a = fmaf(xe.x,w.x,a); a = fmaf(xe.y,w.y,a); a = fmaf(xe.z,w.z,a); a = fmaf(xe.w,w.w,a);
    }
    post[idx] = a;
  }
  __syncthreads();
  // reparam
  {
    float mu = post[s * 128 + d];
    float lv = post[s * 128 + 64 + d];
    float sv = eps_noise[(size_t)b * 512 + tid] * __expf(0.5f * lv) + mu;
    sl[tid] = sv;
    SLOTS[(size_t)b * 512 + tid] = sv;
  }
  __syncthreads();
  // q = slots @ Wq.T + bq  -> hid[0..511]
  {
    const float* xr = sl + s * 64; const float* wr = Wq + d * 64;
    float a = bq[d];
    #pragma unroll
    for (int ec = 0; ec < 16; ec++) {
      float4 xe = ((const float4*)xr)[ec]; float4 w = ((const float4*)wr)[ec];
      a = fmaf(xe.x,w.x,a); a = fmaf(xe.y,w.y,a); a = fmaf(xe.z,w.z,a); a = fmaf(xe.w,w.w,a);
    }
    hid[tid] = a;
  }
  __syncthreads();
  // q' = q @ Wk, c = q . bk ; zero accumulators
  {
    float acc = 0.f;
    #pragma unroll 8
    for (int dd = 0; dd < 64; dd++) acc = fmaf(hid[s * 64 + dd], Wk[dd * 64 + d], acc);
    QP[(size_t)b * 1024 + s * 64 + d] = f2bf(acc);
    float part = wredsum(hid[tid] * bk[d]);
    if ((tid & 63) == 0) Cb[b * 16 + s] = part;
    QP[(size_t)b * 1024 + 512 + tid] = 0;   // zero A rows 8..15
    Ubuf[b * 512 + tid] = 0.f;
    if (tid < 8) { Sbuf[b * 8 + tid] = 0.f; KLb[b * 8 + tid] = 0.f; Cb[b * 16 + 8 + tid] = 0.f; }
  }
}

// ---------------- k_attn: per-512px chunk: QK^T softmax + Uraw/S accumulate ----
__global__ __launch_bounds__(256, 4) void k_attn(
    const u16* __restrict__ XH, const u16* __restrict__ QP,
    const float* __restrict__ Cb,
    float* __restrict__ Ubuf, float* __restrict__ Sbuf)
{
  __shared__ float attn[8][516];
  __shared__ float upd[512];
  const int tid  = threadIdx.x;
  const int lane = tid & 63, wv = tid >> 6;
  const int col  = lane & 15, kg = lane >> 4;
  const int b    = blockIdx.x >> 3;
  const int chunk = blockIdx.x & 7;
  const u16* Xb = XH + ((size_t)b * N_ + chunk * 512) * 64;

  upd[tid] = 0.f; upd[tid + 256] = 0.f;

  union { uint4 q; s16x8 v; } a0, a1;
  const u16* qr = QP + (size_t)b * 1024 + col * 64 + kg * 8;
  a0.q = *(const uint4*)(qr);
  a1.q = *(const uint4*)(qr + 32);
  float4 cv = *(const float4*)(Cb + b * 16 + kg * 4);   // rows 8..15 read zeros
  __syncthreads();

  // pass A: dots via MFMA + in-fragment softmax over 8 slots
  float s_loc[4] = {0.f, 0.f, 0.f, 0.f};
  const int jb = wv * 128;
  #pragma unroll 2
  for (int t = 0; t < 8; t++) {
    const u16* kp = Xb + (size_t)(jb + t * 16 + col) * 64 + kg * 8;
    union { uint4 q; s16x8 v; } b0, b1;
    b0.q = *(const uint4*)(kp);
    b1.q = *(const uint4*)(kp + 32);
    f32x4 acc = {0.f, 0.f, 0.f, 0.f};
    acc = __builtin_amdgcn_mfma_f32_16x16x32_bf16(a0.v, b0.v, acc, 0, 0, 0);
    acc = __builtin_amdgcn_mfma_f32_16x16x32_bf16(a1.v, b1.v, acc, 0, 0, 0);
    float d0 = (acc[0] + cv.x) * SCALE_, d1 = (acc[1] + cv.y) * SCALE_;
    float d2 = (acc[2] + cv.z) * SCALE_, d3 = (acc[3] + cv.w) * SCALE_;
    float m4 = fmaxf(fmaxf(d0, d1), fmaxf(d2, d3));
    float m8 = fmaxf(m4, __shfl_xor(m4, 16, 64));
    float e0 = __expf(d0 - m8), e1 = __expf(d1 - m8);
    float e2 = __expf(d2 - m8), e3 = __expf(d3 - m8);
    float s4 = e0 + e1 + e2 + e3;
    float s8 = s4 + __shfl_xor(s4, 16, 64);
    float rinv = 1.0f / s8;
    float v0 = fmaf(e0, rinv, EPS_), v1 = fmaf(e1, rinv, EPS_);
    float v2 = fmaf(e2, rinv, EPS_), v3 = fmaf(e3, rinv, EPS_);
    if (kg < 2) {
      int j = jb + t * 16 + col;
      attn[kg*4+0][j] = v0; attn[kg*4+1][j] = v1;
      attn[kg*4+2][j] = v2; attn[kg*4+3][j] = v3;
      s_loc[0] += v0; s_loc[1] += v1; s_loc[2] += v2; s_loc[3] += v3;
    }
  }
  #pragma unroll
  for (int r = 0; r < 4; r++) {
    #pragma unroll
    for (int o = 1; o < 16; o <<= 1) s_loc[r] += __shfl_xor(s_loc[r], o, 64);
  }
  if (kg < 2 && col == 0) {
    #pragma unroll
    for (int r = 0; r < 4; r++) atomicAdd(&Sbuf[b * 8 + kg * 4 + r], s_loc[r]);
  }

  // pass B: Uraw += attn * xhat (wave-local attn rows -> no barrier needed)
  const int pxo  = lane >> 4;       // 0..3
  const int dimc = lane & 15;       // dims dimc*4 .. +3
  float u[8][4];
  #pragma unroll
  for (int i = 0; i < 8; i++)
    #pragma unroll
    for (int dd = 0; dd < 4; dd++) u[i][dd] = 0.f;
  #pragma unroll 4
  for (int jg = 0; jg < 32; jg++) {
    int j = jb + jg * 4 + pxo;
    uint2 xv2 = *(const uint2*)(Xb + (size_t)j * 64 + dimc * 4);
    float x0, x1, x2, x3;
    bf2x2(xv2.x, x0, x1); bf2x2(xv2.y, x2, x3);
    #pragma unroll
    for (int i = 0; i < 8; i++) {
      float a = attn[i][j];
      u[i][0] = fmaf(a, x0, u[i][0]); u[i][1] = fmaf(a, x1, u[i][1]);
      u[i][2] = fmaf(a, x2, u[i][2]); u[i][3] = fmaf(a, x3, u[i][3]);
    }
  }
  #pragma unroll
  for (int i = 0; i < 8; i++)
    #pragma unroll
    for (int dd = 0; dd < 4; dd++)
      atomicAdd(&upd[i * 64 + dimc * 4 + dd], u[i][dd]);
  __syncthreads();
  atomicAdd(&Ubuf[(size_t)b * 512 + tid], upd[tid]);
  atomicAdd(&Ubuf[(size_t)b * 512 + 256 + tid], upd[tid + 256]);
}

// ---------------- k_update: per-batch GRU/MLP/post/KL + next q/q'/c ----------
__global__ __launch_bounds__(512) void k_update(
    float* __restrict__ SLOTS, const float* __restrict__ Ubuf_c, float* __restrict__ Ubuf,
    float* __restrict__ Sbuf, const float* __restrict__ PRIOR, float* __restrict__ KLb,
    u16* __restrict__ QP, float* __restrict__ Cb,
    const float* __restrict__ npf_g, const float* __restrict__ npf_b,
    const float* __restrict__ Wq, const float* __restrict__ bq,
    const float* __restrict__ Wk, const float* __restrict__ bk,
    const float* __restrict__ Wv, const float* __restrict__ bv,
    const float* __restrict__ sr_W1, const float* __restrict__ sr_b1,
    const float* __restrict__ sr_W2, const float* __restrict__ sr_b2,
    const float* __restrict__ gWih, const float* __restrict__ gWhh,
    const float* __restrict__ gbih, const float* __restrict__ gbhh,
    const float* __restrict__ mW1, const float* __restrict__ mb1,
    const float* __restrict__ mW2, const float* __restrict__ mb2,
    float* __restrict__ out, int last)
{
  __shared__ float sl[512], sp[512], upd[512], lnb[512], hid[1024], post[1024];
  const int tid = threadIdx.x, b = blockIdx.x;
  const int s = tid >> 6, d = tid & 63;

  {
    float sv = SLOTS[(size_t)b * 512 + tid];
    sl[tid] = sv; sp[tid] = sv;
    upd[tid] = Ubuf_c[b * 512 + tid] * (1.0f / Sbuf[b * 8 + s]);
  }
  __syncthreads();
  // updates = (Uraw/S) @ Wv.T + bv  -> lnb
  {
    const float* xr = upd + s * 64; const float* wr = Wv + d * 64;
    float a = bv[d];
    #pragma unroll
    for (int ec = 0; ec < 16; ec++) {
      float4 xe = ((const float4*)xr)[ec]; float4 w = ((const float4*)wr)[ec];
      a = fmaf(xe.x,w.x,a); a = fmaf(xe.y,w.y,a); a = fmaf(xe.z,w.z,a); a = fmaf(xe.w,w.w,a);
    }
    lnb[tid] = a;
  }
  __syncthreads();
  // GRU + LN(GRU out) -> upd
  {
    const float* ur  = lnb + s * 64;
    const float* hr  = sp + s * 64;
    const float* wi0 = gWih + d * 64;
    const float* wi1 = gWih + (64 + d) * 64;
    const float* wi2 = gWih + (128 + d) * 64;
    const float* wh0 = gWhh + d * 64;
    const float* wh1 = gWhh + (64 + d) * 64;
    const float* wh2 = gWhh + (128 + d) * 64;
    float air=0.f, aiz=0.f, ain=0.f, ahr=0.f, ahz=0.f, ahn=0.f;
    #pragma unroll
    for (int ec = 0; ec < 16; ec++) {
      float4 xe = ((const float4*)ur)[ec];
      float4 he = ((const float4*)hr)[ec];
      float4 w;
      w = ((const float4*)wi0)[ec];
      air = fmaf(xe.x,w.x,air); air = fmaf(xe.y,w.y,air);
      air = fmaf(xe.z,w.z,air); air = fmaf(xe.w,w.w,air);
      w = ((const float4*)wi1)[ec];
      aiz = fmaf(xe.x,w.x,aiz); aiz = fmaf(xe.y,w.y,aiz);
      aiz = fmaf(xe.z,w.z,aiz); aiz = fmaf(xe.w,w.w,aiz);
      w = ((const float4*)wi2)[ec];
      ain = fmaf(xe.x,w.x,ain); ain = fmaf(xe.y,w.y,ain);
      ain = fmaf(xe.z,w.z,ain); ain = fmaf(xe.w,w.w,ain);
      w = ((const float4*)wh0)[ec];
      ahr = fmaf(he.x,w.x,ahr); ahr = fmaf(he.y,w.y,ahr);
      ahr = fmaf(he.z,w.z,ahr); ahr = fmaf(he.w,w.w,ahr);
      w = ((const float4*)wh1)[ec];
      ahz = fmaf(he.x,w.x,ahz); ahz = fmaf(he.y,w.y,ahz);
      ahz = fmaf(he.z,w.z,ahz); ahz = fmaf(he.w,w.w,ahz);
      w = ((const float4*)wh2)[ec];
      ahn = fmaf(he.x,w.x,ahn); ahn = fmaf(he.y,w.y,ahn);
      ahn = fmaf(he.z,w.z,ahn); ahn = fmaf(he.w,w.w,ahn);
    }
    float rr = 1.0f / (1.0f + __expf(-(air + gbih[d]      + ahr + gbhh[d])));
    float zz = 1.0f / (1.0f + __expf(-(aiz + gbih[64 + d] + ahz + gbhh[64 + d])));
    float nn = tanhf(ain + gbih[128 + d] + rr * (ahn + gbhh[128 + d]));
    float hnew = (1.0f - zz) * nn + zz * sp[tid];
    sl[tid] = hnew;
    float mm = wredsum(hnew) * (1.0f / 64.0f);
    float cc = hnew - mm;
    float va = wredsum(cc * cc) * (1.0f / 64.0f);
    upd[tid] = cc * rsqrtf(va + 1e-5f) * npf_g[d] + npf_b[d];
  }
  __syncthreads();
  // mlp hidden = relu(LNout @ mW1.T + mb1)
  #pragma unroll
  for (int kk = 0; kk < 2; kk++) {
    int idx = tid + kk * 512; int s2 = idx >> 7, h = idx & 127;
    const float* xr = upd + s2 * 64; const float* wr = mW1 + h * 64;
    float a = mb1[h];
    #pragma unroll
    for (int ec = 0; ec < 16; ec++) {
      float4 xe = ((const float4*)xr)[ec]; float4 w = ((const float4*)wr)[ec];
      a = fmaf(xe.x,w.x,a); a = fmaf(xe.y,w.y,a); a = fmaf(xe.z,w.z,a); a = fmaf(xe.w,w.w,a);
    }
    hid[idx] = fmaxf(a, 0.f);
  }
  __syncthreads();
  // slots += hid @ mW2.T + mb2
  {
    const float* hh = hid + s * 128; const float* wr = mW2 + d * 128;
    float a = mb2[d];
    #pragma unroll
    for (int ec = 0; ec < 32; ec++) {
      float4 xe = ((const float4*)hh)[ec]; float4 w = ((const float4*)wr)[ec];
      a = fmaf(xe.x,w.x,a); a = fmaf(xe.y,w.y,a); a = fmaf(xe.z,w.z,a); a = fmaf(xe.w,w.w,a);
    }
    sl[tid] = sl[tid] + a;
  }
  __syncthreads();
  // post hidden
  #pragma unroll
  for (int kk = 0; kk < 2; kk++) {
    int idx = tid + kk * 512; int s2 = idx >> 7, h = idx & 127;
    const float* xr = sl + s2 * 64; const float* wr = sr_W1 + h * 64;
    float a = sr_b1[h];
    #pragma unroll
    for (int ec = 0; ec < 16; ec++) {
      float4 xe = ((const float4*)xr)[ec]; float4 w = ((const float4*)wr)[ec];
      a = fmaf(xe.x,w.x,a); a = fmaf(xe.y,w.y,a); a = fmaf(xe.z,w.z,a); a = fmaf(xe.w,w.w,a);
    }
    hid[idx] = fmaxf(a, 0.f);
  }
  __syncthreads();
  // post
  #pragma unroll
  for (int kk = 0; kk < 2; kk++) {
    int idx = tid + kk * 512; int s2 = idx >> 7, o = idx & 127;
    const float* hh = hid + s2 * 128; const float* wr = sr_W2 + o * 128;
    float a = sr_b2[o];
    #pragma unroll
    for (int ec = 0; ec < 32; ec++) {
      float4 xe = ((const float4*)hh)[ec]; float4 w = ((const float4*)wr)[ec];
      a = fmaf(xe.x,w.x,a); a = fmaf(xe.y,w.y,a); a = fmaf(xe.z,w.z,a); a = fmaf(xe.w,w.w,a);
    }
    post[idx] = a;
  }
  __syncthreads();
  // KL accumulate + next q (-> upd)
  {
    float m_po = post[s * 128 + d],  lv_po = post[s * 128 + 64 + d];
    float m_pr = PRIOR[(size_t)b * 1024 + s * 128 + d];
    float lv_pr = PRIOR[(size_t)b * 1024 + s * 128 + 64 + d];
    float dm = m_po - m_pr;
    float term = lv_pr - lv_po + (__expf(lv_po) + dm * dm) * __expf(-lv_pr) - 1.0f;
    float tsum = wredsum(term);
    if ((tid & 63) == 0) {
      float k2 = KLb[b * 8 + s] + 0.5f * tsum;
      KLb[b * 8 + s] = k2;
      if (last) out[OUT_SLOTS_ + b * 8 + s] = k2;
    }
    const float* xr = sl + s * 64; const float* wr = Wq + d * 64;
    float a = bq[d];
    #pragma unroll
    for (int ec = 0; ec < 16; ec++) {
      float4 xe = ((const float4*)xr)[ec]; float4 w = ((const float4*)wr)[ec];
      a = fmaf(xe.x,w.x,a); a = fmaf(xe.y,w.y,a); a = fmaf(xe.z,w.z,a); a = fmaf(xe.w,w.w,a);
    }
    upd[tid] = a;
  }
  __syncthreads();
  // q' = q @ Wk, c = q . bk ; writeback + zero accumulators
  {
    float acc = 0.f;
    #pragma unroll 8
    for (int dd = 0; dd < 64; dd++) acc = fmaf(upd[s * 64 + dd], Wk[dd * 64 + d], acc);
    QP[(size_t)b * 1024 + s * 64 + d] = f2bf(acc);
    float part = wredsum(upd[tid] * bk[d]);
    if ((tid & 63) == 0) Cb[b * 16 + s] = part;
    SLOTS[(size_t)b * 512 + tid] = sl[tid];
    if (last) out[(size_t)b * 512 + tid] = sl[tid];
    Ubuf[b * 512 + tid] = 0.f;
    if (tid < 8) Sbuf[b * 8 + tid] = 0.f;
  }
}

extern "C" void kernel_launch(void* const* d_in, const int* in_sizes, int n_in,
                              void* d_out, int out_size, void* d_ws, size_t ws_size,
                              hipStream_t stream) {
  (void)in_sizes; (void)n_in; (void)out_size; (void)ws_size;
  const float* inputs      = (const float*)d_in[0];
  const float* slots0      = (const float*)d_in[1];
  const float* prior_slots = (const float*)d_in[2];
  const float* eps_noise   = (const float*)d_in[3];
  const float* ni_g  = (const float*)d_in[4];
  const float* ni_b  = (const float*)d_in[5];
  const float* npf_g = (const float*)d_in[6];
  const float* npf_b = (const float*)d_in[7];
  const float* Wq = (const float*)d_in[8];   const float* bq = (const float*)d_in[9];
  const float* Wk = (const float*)d_in[10];  const float* bk = (const float*)d_in[11];
  const float* Wv = (const float*)d_in[12];  const float* bv = (const float*)d_in[13];
  const float* sr_W1 = (const float*)d_in[14]; const float* sr_b1 = (const float*)d_in[15];
  const float* sr_W2 = (const float*)d_in[16]; const float* sr_b2 = (const float*)d_in[17];
  const float* pr_W1 = (const float*)d_in[18]; const float* pr_b1 = (const float*)d_in[19];
  const float* pr_W2 = (const float*)d_in[20]; const float* pr_b2 = (const float*)d_in[21];
  const float* gWih = (const float*)d_in[22]; const float* gWhh = (const float*)d_in[23];
  const float* gbih = (const float*)d_in[24]; const float* gbhh = (const float*)d_in[25];
  const float* mW1 = (const float*)d_in[26]; const float* mb1 = (const float*)d_in[27];
  const float* mW2 = (const float*)d_in[28]; const float* mb2 = (const float*)d_in[29];

  char* ws = (char*)d_ws;
  u16*   XH    = (u16*)  (ws);                     // 134217728 B
  float* Ubuf  = (float*)(ws + 134217728);         //   524288 B
  float* Sbuf  = (float*)(ws + 134742016);         //     8192 B
  u16*   QP    = (u16*)  (ws + 134750208);         //   524288 B
  float* Cb    = (float*)(ws + 135274496);         //    16384 B
  float* SLOTS = (float*)(ws + 135290880);         //   524288 B
  float* PRIOR = (float*)(ws + 135815168);         //  1048576 B
  float* KLb   = (float*)(ws + 136863744);         //     8192 B

  k_ln<<<dim3(4096), dim3(256), 0, stream>>>(inputs, ni_g, ni_b, XH);
  k_init<<<dim3(256), dim3(512), 0, stream>>>(
      slots0, prior_slots, eps_noise,
      sr_W1, sr_b1, sr_W2, sr_b2, pr_W1, pr_b1, pr_W2, pr_b2,
      Wq, bq, Wk, bk, SLOTS, PRIOR, KLb, QP, Cb, Ubuf, Sbuf);
  for (int it = 0; it < 3; it++) {
    k_attn<<<dim3(2048), dim3(256), 0, stream>>>(XH, QP, Cb, Ubuf, Sbuf);
    k_update<<<dim3(256), dim3(512), 0, stream>>>(
        SLOTS, Ubuf, Ubuf, Sbuf, PRIOR, KLb, QP, Cb,
        npf_g, npf_b, Wq, bq, Wk, bk, Wv, bv,
        sr_W1, sr_b1, sr_W2, sr_b2, gWih, gWhh, gbih, gbhh,
        mW1, mb1, mW2, mb2, (float*)d_out, it == 2);
  }
}

// Round 3
// 768.176 us; speedup vs baseline: 1.7707x; 1.5782x over previous
//
#include <hip/hip_runtime.h>
#include <cstdint>
#include <cstddef>

// SlotAttentionV2 forward, MI355X — round 3 (= round 2 resubmit; R2 bench died
// to a container-level infra failure with no kernel error; source re-audited
// for OOB/alignment/graph-capture hazards — none found).
//  * k_setup: precompute fused weights once:
//      WF  = gWih @ Wv   (192x64), bF = gWih@bv + gbih      (GRU input path)
//      WQKs = SCALE * Wq.T @ Wk (64x64), bQKs = SCALE * bq@Wk
//      wcs  = SCALE * Wq.T @ bk, c0s = SCALE * bq.bk        (dot bias)
//    -> k_update loses the Wv GEMM phase and the q->q' serial pair (10 -> 7 phases)
//    -> k_attn dots arrive pre-scaled (SCALE=2^-3 folds into bf16 losslessly)
//  * k_attn: no atomics at all. Per-wave shuffle reduction -> LDS wave slices ->
//    one barrier -> per-chunk partials Upart[b*8+c][512], Spart[b*8+c][8].
//    Explicit K-frag prefetch pipeline in pass A.
//  * k_init/k_update: grid 512 x 256 (4 slots per block, all phases per-slot
//    independent) -> 2 blocks/CU, lighter barriers.

#define B_   256
#define N_   4096
#define EPS_   1e-8f
#define SCALE_ 0.125f
#define OUT_SLOTS_ (B_ * 8 * 64)   // 131072

typedef unsigned short u16;
typedef unsigned int   u32;
typedef short s16x8 __attribute__((ext_vector_type(8)));
typedef float f32x4 __attribute__((ext_vector_type(4)));

__device__ inline float bf2f(u16 u) {
  union { u32 i; float f; } c; c.i = ((u32)u) << 16; return c.f;
}
__device__ inline u16 f2bf(float f) {
  union { u32 i; float f; } c; c.f = f;
  return (u16)((c.i + 0x7fffu + ((c.i >> 16) & 1u)) >> 16);
}
__device__ inline void bf2x2(u32 u, float& lo, float& hi) {
  union { u32 i; float f; } a, b;
  a.i = u << 16; b.i = u & 0xffff0000u;
  lo = a.f; hi = b.f;
}
__device__ inline float wredsum(float v) {
  #pragma unroll
  for (int o = 32; o; o >>= 1) v += __shfl_xor(v, o, 64);
  return v;
}
__device__ inline float dot64(const float* __restrict__ x, const float* __restrict__ w, float a) {
  #pragma unroll
  for (int ec = 0; ec < 16; ec++) {
    float4 xe = ((const float4*)x)[ec]; float4 we = ((const float4*)w)[ec];
    a = fmaf(xe.x, we.x, a); a = fmaf(xe.y, we.y, a);
    a = fmaf(xe.z, we.z, a); a = fmaf(xe.w, we.w, a);
  }
  return a;
}
__device__ inline float dot128(const float* __restrict__ x, const float* __restrict__ w, float a) {
  #pragma unroll
  for (int ec = 0; ec < 32; ec++) {
    float4 xe = ((const float4*)x)[ec]; float4 we = ((const float4*)w)[ec];
    a = fmaf(xe.x, we.x, a); a = fmaf(xe.y, we.y, a);
    a = fmaf(xe.z, we.z, a); a = fmaf(xe.w, we.w, a);
  }
  return a;
}

// ---------------- k_ln: LN(inputs) -> xhat bf16 ----------------
__global__ __launch_bounds__(256) void k_ln(
    const float* __restrict__ x, const float* __restrict__ gg,
    const float* __restrict__ bb, u16* __restrict__ XH)
{
  const int tid = threadIdx.x;
  const int xc = tid & 3;
  const int rloc = tid >> 2;
  float4 g4[4], b4[4];
  #pragma unroll
  for (int j = 0; j < 4; j++) {
    g4[j] = *(const float4*)(gg + xc * 16 + j * 4);
    b4[j] = *(const float4*)(bb + xc * 16 + j * 4);
  }
  for (size_t base = (size_t)blockIdx.x * 64; base < (size_t)B_ * N_;
       base += (size_t)gridDim.x * 64) {
    const size_t row = base + rloc;
    const float* xr = x + row * 64 + xc * 16;
    float4 xv[4];
    #pragma unroll
    for (int j = 0; j < 4; j++) xv[j] = ((const float4*)xr)[j];
    float s = 0.f;
    #pragma unroll
    for (int j = 0; j < 4; j++) s += xv[j].x + xv[j].y + xv[j].z + xv[j].w;
    s += __shfl_xor(s, 1, 64); s += __shfl_xor(s, 2, 64);
    const float m = s * (1.0f / 64.0f);
    float vs = 0.f;
    #pragma unroll
    for (int j = 0; j < 4; j++) {
      float a0 = xv[j].x - m, a1 = xv[j].y - m, a2 = xv[j].z - m, a3 = xv[j].w - m;
      vs += a0*a0 + a1*a1 + a2*a2 + a3*a3;
    }
    vs += __shfl_xor(vs, 1, 64); vs += __shfl_xor(vs, 2, 64);
    const float rs = rsqrtf(vs * (1.0f / 64.0f) + 1e-5f);
    u32 pk[8];
    #pragma unroll
    for (int j = 0; j < 4; j++) {
      float h0 = (xv[j].x - m) * rs * g4[j].x + b4[j].x;
      float h1 = (xv[j].y - m) * rs * g4[j].y + b4[j].y;
      float h2 = (xv[j].z - m) * rs * g4[j].z + b4[j].z;
      float h3 = (xv[j].w - m) * rs * g4[j].w + b4[j].w;
      pk[j*2+0] = (u32)f2bf(h0) | ((u32)f2bf(h1) << 16);
      pk[j*2+1] = (u32)f2bf(h2) | ((u32)f2bf(h3) << 16);
    }
    u32* dst = (u32*)(XH + row * 64 + xc * 16);
    ((uint4*)dst)[0] = make_uint4(pk[0], pk[1], pk[2], pk[3]);
    ((uint4*)dst)[1] = make_uint4(pk[4], pk[5], pk[6], pk[7]);
  }
}

// ---------------- k_setup: fused weight precompute (once) ----------------
__global__ __launch_bounds__(256) void k_setup(
    const float* __restrict__ gWih, const float* __restrict__ gbih,
    const float* __restrict__ Wv,   const float* __restrict__ bv,
    const float* __restrict__ Wq,   const float* __restrict__ bq,
    const float* __restrict__ Wk,   const float* __restrict__ bk,
    float* __restrict__ WF, float* __restrict__ bF,
    float* __restrict__ WQKs, float* __restrict__ bQKs,
    float* __restrict__ wcs, float* __restrict__ c0s)
{
  const int gid = blockIdx.x * 256 + threadIdx.x;
  if (gid < 12288) {            // WF[r][e] = sum_d gWih[r][d]*Wv[d][e]
    int r = gid >> 6, e = gid & 63;
    float a = 0.f;
    #pragma unroll 8
    for (int d = 0; d < 64; d++) a = fmaf(gWih[r*64+d], Wv[d*64+e], a);
    WF[gid] = a;
  } else if (gid < 16384) {     // WQKs[t][e] = S * sum_d Wq[d][t]*Wk[d][e]
    int o = gid - 12288; int t = o >> 6, e = o & 63;
    float a = 0.f;
    #pragma unroll 8
    for (int d = 0; d < 64; d++) a = fmaf(Wq[d*64+t], Wk[d*64+e], a);
    WQKs[o] = a * SCALE_;
  } else if (gid < 16576) {     // bF[r] = gbih[r] + sum_d gWih[r][d]*bv[d]
    int r = gid - 16384;
    float a = gbih[r];
    #pragma unroll 8
    for (int d = 0; d < 64; d++) a = fmaf(gWih[r*64+d], bv[d], a);
    bF[r] = a;
  } else if (gid < 16640) {     // bQKs[e] = S * sum_d bq[d]*Wk[d][e]
    int e = gid - 16576;
    float a = 0.f;
    #pragma unroll 8
    for (int d = 0; d < 64; d++) a = fmaf(bq[d], Wk[d*64+e], a);
    bQKs[e] = a * SCALE_;
  } else if (gid < 16704) {     // wcs[t] = S * sum_d Wq[d][t]*bk[d]
    int t = gid - 16640;
    float a = 0.f;
    #pragma unroll 8
    for (int d = 0; d < 64; d++) a = fmaf(Wq[d*64+t], bk[d], a);
    wcs[t] = a * SCALE_;
  } else if (gid == 16704) {    // c0s = S * bq.bk
    float a = 0.f;
    #pragma unroll 8
    for (int d = 0; d < 64; d++) a = fmaf(bq[d], bk[d], a);
    c0s[0] = a * SCALE_;
  }
}

// ---------------- k_init: prior / reparam / q' / zero state (4 slots/block) ----
__global__ __launch_bounds__(256) void k_init(
    const float* __restrict__ slots0, const float* __restrict__ prior_slots,
    const float* __restrict__ eps_noise,
    const float* __restrict__ sr_W1, const float* __restrict__ sr_b1,
    const float* __restrict__ sr_W2, const float* __restrict__ sr_b2,
    const float* __restrict__ pr_W1, const float* __restrict__ pr_b1,
    const float* __restrict__ pr_W2, const float* __restrict__ pr_b2,
    const float* __restrict__ WQKs, const float* __restrict__ bQKs,
    const float* __restrict__ wcs, const float* __restrict__ c0s,
    float* __restrict__ SLOTS, float* __restrict__ PRIOR, float* __restrict__ KLb,
    u16* __restrict__ QP, float* __restrict__ Cb)
{
  __shared__ float sl[256], hid[512], pst[512];
  const int tid = threadIdx.x;
  const int w = tid >> 6, lane = tid & 63;
  const int gs0 = blockIdx.x * 4;          // 4 consecutive global slots, same batch
  const int b = gs0 >> 3;
  const int gs = gs0 + w;

  sl[tid] = slots0[(size_t)gs0 * 64 + tid];
  // prior hidden = relu(prior_slots @ pr_W1.T + pr_b1)
  #pragma unroll
  for (int kk = 0; kk < 2; kk++) {
    int idx = tid + kk * 256; int sloc = idx >> 7, h = idx & 127;
    float a = dot64(prior_slots + (size_t)(gs0 + sloc) * 64, pr_W1 + h * 64, pr_b1[h]);
    hid[idx] = fmaxf(a, 0.f);
  }
  __syncthreads();
  // prior = hid @ pr_W2.T + pr_b2 -> global
  #pragma unroll
  for (int kk = 0; kk < 2; kk++) {
    int idx = tid + kk * 256; int sloc = idx >> 7, o = idx & 127;
    PRIOR[(size_t)(gs0 + sloc) * 128 + o] =
        dot128(hid + sloc * 128, pr_W2 + o * 128, pr_b2[o]);
  }
  __syncthreads();
  // sms hidden
  #pragma unroll
  for (int kk = 0; kk < 2; kk++) {
    int idx = tid + kk * 256; int sloc = idx >> 7, h = idx & 127;
    float a = dot64(sl + sloc * 64, sr_W1 + h * 64, sr_b1[h]);
    hid[idx] = fmaxf(a, 0.f);
  }
  __syncthreads();
  // sms = hid @ sr_W2.T + sr_b2
  #pragma unroll
  for (int kk = 0; kk < 2; kk++) {
    int idx = tid + kk * 256; int sloc = idx >> 7, o = idx & 127;
    pst[idx] = dot128(hid + sloc * 128, sr_W2 + o * 128, sr_b2[o]);
  }
  __syncthreads();
  // reparam
  {
    float mu = pst[w * 128 + lane];
    float lv = pst[w * 128 + 64 + lane];
    float sv = eps_noise[(size_t)gs * 64 + lane] * __expf(0.5f * lv) + mu;
    sl[tid] = sv;
    SLOTS[(size_t)gs * 64 + lane] = sv;
  }
  __syncthreads();
  // q' (fused, pre-scaled) + c + zero state
  {
    float a = bQKs[lane];
    #pragma unroll 8
    for (int t2 = 0; t2 < 64; t2++) a = fmaf(sl[w * 64 + t2], WQKs[t2 * 64 + lane], a);
    QP[(size_t)b * 1024 + (gs & 7) * 64 + lane] = f2bf(a);
    float part = wredsum(sl[tid] * wcs[lane]);
    if (lane == 0) { Cb[b * 16 + (gs & 7)] = part + c0s[0]; KLb[gs] = 0.f; }
    QP[(size_t)b * 1024 + 512 + (blockIdx.x & 1) * 256 + tid] = 0;  // A rows 8..15
    if ((blockIdx.x & 1) == 0 && tid < 8) Cb[b * 16 + 8 + tid] = 0.f;
  }
}

// ---------------- k_attn: per-512px chunk, atomic-free, one barrier ----------
__global__ __launch_bounds__(256, 4) void k_attn(
    const u16* __restrict__ XH, const u16* __restrict__ QP,
    const float* __restrict__ Cb,
    float* __restrict__ Upart, float* __restrict__ Spart)
{
  __shared__ float attn[8][516];
  __shared__ float updw[4][512];
  __shared__ float sS[4][8];
  const int tid  = threadIdx.x;
  const int lane = tid & 63, wv = tid >> 6;
  const int col  = lane & 15, kg = lane >> 4;
  const int bc   = blockIdx.x;           // b*8 + chunk
  const int b    = bc >> 3;
  const u16* Xb = XH + (size_t)bc * 512 * 64;

  union { uint4 q; s16x8 v; } a0, a1;
  const u16* qr = QP + (size_t)b * 1024 + col * 64 + kg * 8;
  a0.q = *(const uint4*)(qr);
  a1.q = *(const uint4*)(qr + 32);
  float4 cv = *(const float4*)(Cb + b * 16 + kg * 4);   // rows 8..15 read zeros

  // pass A: pre-scaled dots via MFMA + in-fragment softmax over 8 slots
  const int jb = wv * 128;
  float s_loc[4] = {0.f, 0.f, 0.f, 0.f};
  union { uint4 q; s16x8 v; } b0, b1, n0, n1;
  {
    const u16* kp = Xb + (size_t)(jb + col) * 64 + kg * 8;
    b0.q = *(const uint4*)kp; b1.q = *(const uint4*)(kp + 32);
  }
  #pragma unroll 1
  for (int t = 0; t < 8; t++) {
    const u16* kn = Xb + (size_t)(jb + (((t + 1) & 7) << 4) + col) * 64 + kg * 8;
    n0.q = *(const uint4*)kn; n1.q = *(const uint4*)(kn + 32);
    f32x4 acc = {0.f, 0.f, 0.f, 0.f};
    acc = __builtin_amdgcn_mfma_f32_16x16x32_bf16(a0.v, b0.v, acc, 0, 0, 0);
    acc = __builtin_amdgcn_mfma_f32_16x16x32_bf16(a1.v, b1.v, acc, 0, 0, 0);
    float d0 = acc[0] + cv.x, d1 = acc[1] + cv.y;
    float d2 = acc[2] + cv.z, d3 = acc[3] + cv.w;
    float m4 = fmaxf(fmaxf(d0, d1), fmaxf(d2, d3));
    float m8 = fmaxf(m4, __shfl_xor(m4, 16, 64));
    float e0 = __expf(d0 - m8), e1 = __expf(d1 - m8);
    float e2 = __expf(d2 - m8), e3 = __expf(d3 - m8);
    float s4 = e0 + e1 + e2 + e3;
    float s8 = s4 + __shfl_xor(s4, 16, 64);
    float rinv = 1.0f / s8;
    float v0 = fmaf(e0, rinv, EPS_), v1 = fmaf(e1, rinv, EPS_);
    float v2 = fmaf(e2, rinv, EPS_), v3 = fmaf(e3, rinv, EPS_);
    if (kg < 2) {
      int j = jb + t * 16 + col;
      attn[kg*4+0][j] = v0; attn[kg*4+1][j] = v1;
      attn[kg*4+2][j] = v2; attn[kg*4+3][j] = v3;
      s_loc[0] += v0; s_loc[1] += v1; s_loc[2] += v2; s_loc[3] += v3;
    }
    b0 = n0; b1 = n1;
  }
  #pragma unroll
  for (int r = 0; r < 4; r++) {
    #pragma unroll
    for (int o = 1; o < 16; o <<= 1) s_loc[r] += __shfl_xor(s_loc[r], o, 64);
  }
  if (kg < 2 && col == 0) {
    #pragma unroll
    for (int r = 0; r < 4; r++) sS[wv][kg * 4 + r] = s_loc[r];
  }

  // pass B: Uraw += attn * xhat; wave-local rows, shuffle-reduced, no atomics
  const int pxo  = lane >> 4;       // 0..3
  const int dimc = lane & 15;       // dims dimc*4 .. +3
  float u[8][4];
  #pragma unroll
  for (int i = 0; i < 8; i++)
    #pragma unroll
    for (int dd = 0; dd < 4; dd++) u[i][dd] = 0.f;
  #pragma unroll 4
  for (int jg = 0; jg < 32; jg++) {
    int j = jb + jg * 4 + pxo;
    uint2 xv2 = *(const uint2*)(Xb + (size_t)j * 64 + dimc * 4);
    float x0, x1, x2, x3;
    bf2x2(xv2.x, x0, x1); bf2x2(xv2.y, x2, x3);
    #pragma unroll
    for (int i = 0; i < 8; i++) {
      float a = attn[i][j];
      u[i][0] = fmaf(a, x0, u[i][0]); u[i][1] = fmaf(a, x1, u[i][1]);
      u[i][2] = fmaf(a, x2, u[i][2]); u[i][3] = fmaf(a, x3, u[i][3]);
    }
  }
  #pragma unroll
  for (int i = 0; i < 8; i++)
    #pragma unroll
    for (int dd = 0; dd < 4; dd++) {
      u[i][dd] += __shfl_xor(u[i][dd], 16, 64);
      u[i][dd] += __shfl_xor(u[i][dd], 32, 64);
    }
  if (lane < 16) {
    #pragma unroll
    for (int i = 0; i < 8; i++)
      #pragma unroll
      for (int dd = 0; dd < 4; dd++)
        updw[wv][i * 64 + lane * 4 + dd] = u[i][dd];
  }
  __syncthreads();
  #pragma unroll
  for (int k2 = 0; k2 < 2; k2++) {
    int idx = tid + k2 * 256;
    Upart[(size_t)bc * 512 + idx] =
        updw[0][idx] + updw[1][idx] + updw[2][idx] + updw[3][idx];
  }
  if (tid < 8)
    Spart[bc * 8 + tid] = sS[0][tid] + sS[1][tid] + sS[2][tid] + sS[3][tid];
}

// ---------------- k_update: fused GRU/MLP/post/KL + next q' (4 slots/block) ----
__global__ __launch_bounds__(256) void k_update(
    float* __restrict__ SLOTS, const float* __restrict__ Upart,
    const float* __restrict__ Spart, const float* __restrict__ PRIOR,
    float* __restrict__ KLb, u16* __restrict__ QP, float* __restrict__ Cb,
    const float* __restrict__ npf_g, const float* __restrict__ npf_b,
    const float* __restrict__ WF, const float* __restrict__ bF,
    const float* __restrict__ gWhh, const float* __restrict__ gbhh,
    const float* __restrict__ WQKs, const float* __restrict__ bQKs,
    const float* __restrict__ wcs, const float* __restrict__ c0s,
    const float* __restrict__ sr_W1, const float* __restrict__ sr_b1,
    const float* __restrict__ sr_W2, const float* __restrict__ sr_b2,
    const float* __restrict__ mW1, const float* __restrict__ mb1,
    const float* __restrict__ mW2, const float* __restrict__ mb2,
    float* __restrict__ out, int last)
{
  __shared__ float uav[256], spl[256], sl[256], lnb[256], hid[512], pst[512];
  const int tid = threadIdx.x;
  const int w = tid >> 6, lane = tid & 63;
  const int gs = blockIdx.x * 4 + w;
  const int b = gs >> 3, s = gs & 7;

  // P1: reduce chunk partials, scale by 1/S, load prev slots
  {
    const float* up = Upart + (size_t)b * 4096 + s * 64 + lane;
    float usum = 0.f;
    #pragma unroll
    for (int c = 0; c < 8; c++) usum += up[c * 512];
    const float* sp2 = Spart + b * 64 + s;
    float Sv = 0.f;
    #pragma unroll
    for (int c = 0; c < 8; c++) Sv += sp2[c * 8];
    uav[tid] = usum * (1.0f / Sv);
    spl[tid] = SLOTS[(size_t)gs * 64 + lane];
  }
  __syncthreads();
  // P2: GRU (Wv folded into WF) + LN
  {
    const float* ur = uav + w * 64;
    const float* hr = spl + w * 64;
    const float* wi0 = WF + lane * 64;
    const float* wi1 = WF + (64 + lane) * 64;
    const float* wi2 = WF + (128 + lane) * 64;
    const float* wh0 = gWhh + lane * 64;
    const float* wh1 = gWhh + (64 + lane) * 64;
    const float* wh2 = gWhh + (128 + lane) * 64;
    float air = 0.f, aiz = 0.f, ain = 0.f, ahr = 0.f, ahz = 0.f, ahn = 0.f;
    #pragma unroll
    for (int ec = 0; ec < 16; ec++) {
      float4 xe = ((const float4*)ur)[ec];
      float4 he = ((const float4*)hr)[ec];
      float4 ww;
      ww = ((const float4*)wi0)[ec];
      air = fmaf(xe.x,ww.x,air); air = fmaf(xe.y,ww.y,air);
      air = fmaf(xe.z,ww.z,air); air = fmaf(xe.w,ww.w,air);
      ww = ((const float4*)wi1)[ec];
      aiz = fmaf(xe.x,ww.x,aiz); aiz = fmaf(xe.y,ww.y,aiz);
      aiz = fmaf(xe.z,ww.z,aiz); aiz = fmaf(xe.w,ww.w,aiz);
      ww = ((const float4*)wi2)[ec];
      ain = fmaf(xe.x,ww.x,ain); ain = fmaf(xe.y,ww.y,ain);
      ain = fmaf(xe.z,ww.z,ain); ain = fmaf(xe.w,ww.w,ain);
      ww = ((const float4*)wh0)[ec];
      ahr = fmaf(he.x,ww.x,ahr); ahr = fmaf(he.y,ww.y,ahr);
      ahr = fmaf(he.z,ww.z,ahr); ahr = fmaf(he.w,ww.w,ahr);
      ww = ((const float4*)wh1)[ec];
      ahz = fmaf(he.x,ww.x,ahz); ahz = fmaf(he.y,ww.y,ahz);
      ahz = fmaf(he.z,ww.z,ahz); ahz = fmaf(he.w,ww.w,ahz);
      ww = ((const float4*)wh2)[ec];
      ahn = fmaf(he.x,ww.x,ahn); ahn = fmaf(he.y,ww.y,ahn);
      ahn = fmaf(he.z,ww.z,ahn); ahn = fmaf(he.w,ww.w,ahn);
    }
    float rr = 1.0f / (1.0f + __expf(-(air + bF[lane]       + ahr + gbhh[lane])));
    float zz = 1.0f / (1.0f + __expf(-(aiz + bF[64 + lane]  + ahz + gbhh[64 + lane])));
    float nn = tanhf(ain + bF[128 + lane] + rr * (ahn + gbhh[128 + lane]));
    float hnew = (1.0f - zz) * nn + zz * spl[tid];
    sl[tid] = hnew;
    float mm = wredsum(hnew) * (1.0f / 64.0f);
    float cc = hnew - mm;
    float va = wredsum(cc * cc) * (1.0f / 64.0f);
    lnb[tid] = cc * rsqrtf(va + 1e-5f) * npf_g[lane] + npf_b[lane];
  }
  __syncthreads();
  // P3: mlp hidden
  #pragma unroll
  for (int kk = 0; kk < 2; kk++) {
    int idx = tid + kk * 256; int sloc = idx >> 7, h = idx & 127;
    float a = dot64(lnb + sloc * 64, mW1 + h * 64, mb1[h]);
    hid[idx] = fmaxf(a, 0.f);
  }
  __syncthreads();
  // P4: slots += hid @ mW2.T + mb2
  sl[tid] += dot128(hid + w * 128, mW2 + lane * 128, mb2[lane]);
  __syncthreads();
  // P5: post hidden
  #pragma unroll
  for (int kk = 0; kk < 2; kk++) {
    int idx = tid + kk * 256; int sloc = idx >> 7, h = idx & 127;
    float a = dot64(sl + sloc * 64, sr_W1 + h * 64, sr_b1[h]);
    hid[idx] = fmaxf(a, 0.f);
  }
  __syncthreads();
  // P6: post
  #pragma unroll
  for (int kk = 0; kk < 2; kk++) {
    int idx = tid + kk * 256; int sloc = idx >> 7, o = idx & 127;
    pst[idx] = dot128(hid + sloc * 128, sr_W2 + o * 128, sr_b2[o]);
  }
  __syncthreads();
  // P7: KL + writeback + next q'/c
  {
    float m_po = pst[w * 128 + lane],  lv_po = pst[w * 128 + 64 + lane];
    float m_pr = PRIOR[(size_t)gs * 128 + lane];
    float lv_pr = PRIOR[(size_t)gs * 128 + 64 + lane];
    float dm = m_po - m_pr;
    float term = lv_pr - lv_po + (__expf(lv_po) + dm * dm) * __expf(-lv_pr) - 1.0f;
    float tsum = wredsum(term);
    if (lane == 0) {
      float k2 = KLb[gs] + 0.5f * tsum;
      KLb[gs] = k2;
      if (last) out[OUT_SLOTS_ + gs] = k2;
    }
    if (last) {
      out[(size_t)gs * 64 + lane] = sl[tid];
    } else {
      SLOTS[(size_t)gs * 64 + lane] = sl[tid];
      float a = bQKs[lane];
      #pragma unroll 8
      for (int t2 = 0; t2 < 64; t2++) a = fmaf(sl[w * 64 + t2], WQKs[t2 * 64 + lane], a);
      QP[(size_t)b * 1024 + s * 64 + lane] = f2bf(a);
      float part = wredsum(sl[tid] * wcs[lane]);
      if (lane == 0) Cb[b * 16 + s] = part + c0s[0];
    }
  }
}

extern "C" void kernel_launch(void* const* d_in, const int* in_sizes, int n_in,
                              void* d_out, int out_size, void* d_ws, size_t ws_size,
                              hipStream_t stream) {
  (void)in_sizes; (void)n_in; (void)out_size; (void)ws_size;
  const float* inputs      = (const float*)d_in[0];
  const float* slots0      = (const float*)d_in[1];
  const float* prior_slots = (const float*)d_in[2];
  const float* eps_noise   = (const float*)d_in[3];
  const float* ni_g  = (const float*)d_in[4];
  const float* ni_b  = (const float*)d_in[5];
  const float* npf_g = (const float*)d_in[6];
  const float* npf_b = (const float*)d_in[7];
  const float* Wq = (const float*)d_in[8];   const float* bq = (const float*)d_in[9];
  const float* Wk = (const float*)d_in[10];  const float* bk = (const float*)d_in[11];
  const float* Wv = (const float*)d_in[12];  const float* bv = (const float*)d_in[13];
  const float* sr_W1 = (const float*)d_in[14]; const float* sr_b1 = (const float*)d_in[15];
  const float* sr_W2 = (const float*)d_in[16]; const float* sr_b2 = (const float*)d_in[17];
  const float* pr_W1 = (const float*)d_in[18]; const float* pr_b1 = (const float*)d_in[19];
  const float* pr_W2 = (const float*)d_in[20]; const float* pr_b2 = (const float*)d_in[21];
  const float* gWih = (const float*)d_in[22]; const float* gWhh = (const float*)d_in[23];
  const float* gbih = (const float*)d_in[24]; const float* gbhh = (const float*)d_in[25];
  const float* mW1 = (const float*)d_in[26]; const float* mb1 = (const float*)d_in[27];
  const float* mW2 = (const float*)d_in[28]; const float* mb2 = (const float*)d_in[29];

  char* ws = (char*)d_ws;
  u16*   XH    = (u16*)  (ws);                     // 134217728 B
  float* Upart = (float*)(ws + 134217728);         //  4194304 B
  float* Spart = (float*)(ws + 138412032);         //    65536 B
  u16*   QP    = (u16*)  (ws + 138477568);         //   524288 B
  float* Cb    = (float*)(ws + 139001856);         //    16384 B
  float* SLOTS = (float*)(ws + 139018240);         //   524288 B
  float* PRIOR = (float*)(ws + 139542528);         //  1048576 B
  float* KLb   = (float*)(ws + 140591104);         //     8192 B
  float* WF    = (float*)(ws + 140599296);         //    49152 B
  float* WQKs  = (float*)(ws + 140648448);         //    16384 B
  float* bF    = (float*)(ws + 140664832);         //      768 B
  float* bQKs  = (float*)(ws + 140665600);         //      256 B
  float* wcs   = (float*)(ws + 140665856);         //      256 B
  float* c0s   = (float*)(ws + 140666112);         //        4 B

  k_setup<<<dim3(66), dim3(256), 0, stream>>>(
      gWih, gbih, Wv, bv, Wq, bq, Wk, bk, WF, bF, WQKs, bQKs, wcs, c0s);
  k_ln<<<dim3(4096), dim3(256), 0, stream>>>(inputs, ni_g, ni_b, XH);
  k_init<<<dim3(512), dim3(256), 0, stream>>>(
      slots0, prior_slots, eps_noise,
      sr_W1, sr_b1, sr_W2, sr_b2, pr_W1, pr_b1, pr_W2, pr_b2,
      WQKs, bQKs, wcs, c0s, SLOTS, PRIOR, KLb, QP, Cb);
  for (int it = 0; it < 3; it++) {
    k_attn<<<dim3(2048), dim3(256), 0, stream>>>(XH, QP, Cb, Upart, Spart);
    k_update<<<dim3(512), dim3(256), 0, stream>>>(
        SLOTS, Upart, Spart, PRIOR, KLb, QP, Cb,
        npf_g, npf_b, WF, bF, gWhh, gbhh, WQKs, bQKs, wcs, c0s,
        sr_W1, sr_b1, sr_W2, sr_b2, mW1, mb1, mW2, mb2,
        (float*)d_out, it == 2);
  }
}